// Round 1
// baseline (7778.481 us; speedup 1.0000x reference)
//
#include <hip/hip_runtime.h>

typedef _Float16 f16;
typedef _Float16 v4h __attribute__((ext_vector_type(4)));
typedef _Float16 v8h __attribute__((ext_vector_type(8)));
typedef float    v4f __attribute__((ext_vector_type(4)));

#define WARM   96
#define LSTEPS 224   // 96 warmup + 128 payload; 64 chunks/dir * 128 = 8192

// workspace layout (bytes)
#define XG_OFF     0ull                 // f16 xg[2][8192][4096]  (128 MB)
#define WHH_OFF    134217728ull         // f16 whh[2][4096][1024] (16 MB)
#define HIST_OFF   150994944ull         // f16 hist[2][8192][1024] (32 MB)
#define HST_OFF    184549376ull         // u32 hst[8][2][16][1024] (1 MB) tag<<16|f16
#define FEATS_OFF  185597952ull         // f32 feats[8192][8]
#define BPW_OFF    185860096ull         // u32 bp[8192] (5x4-bit fields)
#define MISC_OFF   185892864ull         // u32 bestidx
#define WS_NEEDED  185893120ull

__device__ __forceinline__ float sigm(float x) {
  return 1.f / (1.f + exp2f(-1.4426950408889634f * x));
}
__device__ __forceinline__ float tanh_(float x) {
  x = fminf(fmaxf(x, -16.f), 16.f);
  float e = exp2f(2.8853900817779268f * x);
  return (e - 1.f) / (e + 1.f);
}
__device__ __forceinline__ unsigned short f16bits(float x) {
  union { f16 h; unsigned short u; } cv; cv.h = (f16)x; return cv.u;
}

__global__ void k_sentinel(float* out) {
  if (threadIdx.x == 0 && blockIdx.x == 0) out[0] = -12345678.0f;
}

// convert Whh (both dirs) to f16
__global__ void k_prep(const float* __restrict__ wf_, const float* __restrict__ wb_,
                       char* __restrict__ ws) {
  f16* o = (f16*)(ws + WHH_OFF);
  const unsigned int N = 4096u * 1024u;
  for (unsigned int i = blockIdx.x * blockDim.x + threadIdx.x; i < 2u * N;
       i += gridDim.x * blockDim.x) {
    float v = (i < N) ? wf_[i] : wb_[i - N];
    o[i] = (f16)v;
  }
}

// init exchange buffers: parity0 = tag 0 + initial h (h0 for chunk 0, else 0); parity1 poisoned tag
__global__ void k_init(const float* __restrict__ h0, char* __restrict__ ws) {
  unsigned int* hst = (unsigned int*)(ws + HST_OFF);
  const unsigned int TOT = 8u * 2u * 16u * 1024u;
  for (unsigned int idx = blockIdx.x * blockDim.x + threadIdx.x; idx < TOT;
       idx += gridDim.x * blockDim.x) {
    unsigned int cl = idx >> 15, rem = idx & 32767u;
    unsigned int par = rem >> 14, b = (rem >> 10) & 15u, u = rem & 1023u;
    unsigned int w;
    if (par) w = 0xFFFF0000u;
    else {
      unsigned int d = cl >> 2, g = cl & 3u;
      unsigned int chunk = g * 16u + b;
      unsigned short hb = 0;
      if (chunk == 0u) hb = f16bits(h0[d * 1024u + u]);
      w = (unsigned int)hb;            // tag 0 in hi16
    }
    hst[idx] = w;
  }
}

// xg[d][t][r] = doc[t] @ Wih_d.T + (bih+bhh), stored f16.  C = A(8192x1024) * B^T(4096x1024)
__launch_bounds__(256, 2)
__global__ void k_phase1(const float* __restrict__ doc,
                         const float* __restrict__ wih_f, const float* __restrict__ wih_b,
                         const float* __restrict__ bih_f, const float* __restrict__ bhh_f,
                         const float* __restrict__ bih_b, const float* __restrict__ bhh_b,
                         char* __restrict__ ws) {
  const int bx = blockIdx.x, by = blockIdx.y, d = blockIdx.z;
  const float* B  = d ? wih_b : wih_f;
  const float* bi = d ? bih_b : bih_f;
  const float* bh = d ? bhh_b : bhh_f;
  f16* xg = (f16*)(ws + XG_OFF) + (size_t)d * 8192 * 4096;
  __shared__ f16 Al[128][40];
  __shared__ f16 Bl[128][40];
  const int t = threadIdx.x;
  const int w = t >> 6, l = t & 63;
  const int wm = w >> 1, wn = w & 1;
  const int srow = t >> 1, scg = t & 1;
  const int lm = l & 15, lg = l >> 4;
  v4f acc[4][4];
  #pragma unroll
  for (int a = 0; a < 4; a++)
    #pragma unroll
    for (int b2 = 0; b2 < 4; b2++) acc[a][b2] = (v4f){0.f, 0.f, 0.f, 0.f};
  const float* Abase = doc + (size_t)(by * 128 + srow) * 1024;
  const float* Bbase = B   + (size_t)(bx * 128 + srow) * 1024;
  for (int k0 = 0; k0 < 1024; k0 += 32) {
    v4f av[4], bv[4];
    const v4f* pA = (const v4f*)(Abase + k0 + scg * 16);
    const v4f* pB = (const v4f*)(Bbase + k0 + scg * 16);
    #pragma unroll
    for (int i = 0; i < 4; i++) { av[i] = pA[i]; bv[i] = pB[i]; }
    __syncthreads();
    v8h a0, a1, b0, b1;
    #pragma unroll
    for (int j = 0; j < 8; j++) {
      a0[j] = (f16)av[j >> 2][j & 3]; a1[j] = (f16)av[2 + (j >> 2)][j & 3];
      b0[j] = (f16)bv[j >> 2][j & 3]; b1[j] = (f16)bv[2 + (j >> 2)][j & 3];
    }
    *(v8h*)&Al[srow][scg * 16]     = a0;
    *(v8h*)&Al[srow][scg * 16 + 8] = a1;
    *(v8h*)&Bl[srow][scg * 16]     = b0;
    *(v8h*)&Bl[srow][scg * 16 + 8] = b1;
    __syncthreads();
    #pragma unroll
    for (int kt = 0; kt < 2; kt++) {
      const int koff = kt * 16 + lg * 4;
      v4h af[4], bf[4];
      #pragma unroll
      for (int mt = 0; mt < 4; mt++) af[mt] = *(const v4h*)&Al[wm * 64 + mt * 16 + lm][koff];
      #pragma unroll
      for (int nt = 0; nt < 4; nt++) bf[nt] = *(const v4h*)&Bl[wn * 64 + nt * 16 + lm][koff];
      #pragma unroll
      for (int mt = 0; mt < 4; mt++)
        #pragma unroll
        for (int nt = 0; nt < 4; nt++)
          acc[mt][nt] = __builtin_amdgcn_mfma_f32_16x16x16f16(af[mt], bf[nt], acc[mt][nt], 0, 0, 0);
    }
  }
  #pragma unroll
  for (int nt = 0; nt < 4; nt++) {
    const int col = bx * 128 + wn * 64 + nt * 16 + lm;
    const float bias = bi[col] + bh[col];
    #pragma unroll
    for (int mt = 0; mt < 4; mt++) {
      #pragma unroll
      for (int q = 0; q < 4; q++) {
        const int row = by * 128 + wm * 64 + mt * 16 + lg * 4 + q;
        xg[(size_t)row * 4096 + col] = (f16)(acc[mt][nt][q] + bias);
      }
    }
  }
}

// The recurrent engine. 8 clusters (2 dirs x 4) x 32 WGs x 512 thr, 1 WG/CU (VGPR-forced).
// WG k owns units [k*32,k*32+32) => gate rows {g*1024+u}. Weights live in 128 VGPRs/lane as
// MFMA A-fragments. Per step: gates[128 x 16chunks] = Whh_slice @ H via 16x16x16f16 MFMA.
__launch_bounds__(512, 2)
__global__ void k_cluster(const float* __restrict__ h0, const float* __restrict__ c0,
                          char* __restrict__ ws) {
  const int bi = blockIdx.x;
  const int cl = bi & 7, kk = bi >> 3;       // cluster id, WG-in-cluster (XCD-affine heuristic)
  const int d = cl >> 2, g = cl & 3;
  const int ubase = kk * 32;
  const int tid = threadIdx.x;
  const int w = tid >> 6, l = tid & 63;
  const int lm = l & 15, lg = l >> 4;
  const int gt = w >> 1;                     // gate type of this wave: 0=i 1=f 2=g 3=o
  const f16* whh = (const f16*)(ws + WHH_OFF) + (size_t)d * 4096 * 1024;
  const f16* xg  = (const f16*)(ws + XG_OFF)  + (size_t)d * 8192 * 4096;
  f16* hist = (f16*)(ws + HIST_OFF) + (size_t)d * 8192 * 1024;
  unsigned int* hstBase = (unsigned int*)(ws + HST_OFF) + (size_t)cl * (2 * 16 * 1024);

  __shared__ f16 Hl[16][1032];      // [chunk][unit] (+pad)
  __shared__ f16 xgl[16][136];      // [chunk][localrow] (+pad)
  __shared__ float actl[128][17];   // [localrow][chunk]
  __shared__ float cst[32][16];     // [unit][chunk]

  const int row = gt * 1024 + ubase + (w & 1) * 16 + lm;   // global gate row
  v4h wf[64];                       // A-fragments: k = kt*16 + lg*4 + j
  #pragma unroll
  for (int kt = 0; kt < 64; kt++)
    wf[kt] = *(const v4h*)(whh + (size_t)row * 1024 + kt * 16 + lg * 4);

  const int uu = tid >> 4, bb = tid & 15;    // (unit-in-slice / word-seg, chunk-col)
  const int chunkU = g * 16 + bb;
  cst[uu][bb] = (chunkU == 0) ? c0[d * 1024 + ubase + uu] : 0.f;
  const float h0v = (chunkU == 0) ? h0[d * 1024 + ubase + uu] : 0.f;
  __syncthreads();

  for (int s = 0; s < LSTEPS; s++) {
    // xg prefetch (issued before the poll so HBM latency hides under it)
    const int pb = tid >> 5, rg = tid & 31;
    const int rP = (g * 16 + pb) * 128 - WARM + s;
    const int tP = d ? (8191 - rP) : rP;
    uint2 xv = make_uint2(0u, 0u);
    if (rP >= 0)
      xv = *(const uint2*)(xg + (size_t)tP * 4096 + (rg >> 3) * 1024 + ubase + (rg & 7) * 4);

    // poll H words (tag embedded per 32-bit word; double-buffered by parity)
    unsigned long long* rp = (unsigned long long*)(hstBase + (size_t)(s & 1) * (16 * 1024)
                                                   + bb * 1024 + uu * 32);
    unsigned long long vw[16];
    const unsigned int target = (unsigned int)s & 0xffffu;
    for (;;) {
      bool ok = true;
      #pragma unroll
      for (int i = 0; i < 16; i++) {
        vw[i] = __hip_atomic_load(&rp[i], __ATOMIC_RELAXED, __HIP_MEMORY_SCOPE_AGENT);
        ok &= (((unsigned int)vw[i] >> 16) == target) &
              (((unsigned int)(vw[i] >> 48)) == target);
      }
      if (ok) break;
      __builtin_amdgcn_s_sleep(2);
    }
    #pragma unroll
    for (int i = 0; i < 8; i++) {
      unsigned int lo0 = (unsigned int)vw[2 * i] & 0xffffu;
      unsigned int hi0 = (unsigned int)(vw[2 * i] >> 32) & 0xffffu;
      unsigned int lo1 = (unsigned int)vw[2 * i + 1] & 0xffffu;
      unsigned int hi1 = (unsigned int)(vw[2 * i + 1] >> 32) & 0xffffu;
      uint2 pk; pk.x = lo0 | (hi0 << 16); pk.y = lo1 | (hi1 << 16);
      *(uint2*)&Hl[bb][uu * 32 + i * 4] = pk;
    }
    *(uint2*)&xgl[pb][(rg >> 3) * 32 + (rg & 7) * 4] = xv;
    __syncthreads();

    // MFMA: gates(this wave's 16 rows) x 16 chunks, K=1024
    v4f acc0 = (v4f){0.f, 0.f, 0.f, 0.f}, acc1 = (v4f){0.f, 0.f, 0.f, 0.f};
    #pragma unroll
    for (int kt = 0; kt < 64; kt++) {
      v4h bfr = *(const v4h*)&Hl[lm][kt * 16 + lg * 4];
      if (kt & 1) acc1 = __builtin_amdgcn_mfma_f32_16x16x16f16(wf[kt], bfr, acc1, 0, 0, 0);
      else        acc0 = __builtin_amdgcn_mfma_f32_16x16x16f16(wf[kt], bfr, acc0, 0, 0, 0);
    }
    // activation (wave-uniform gate type)
    #pragma unroll
    for (int q = 0; q < 4; q++) {
      const int rowL = w * 16 + lg * 4 + q;           // = gt*32 + unit_offset
      float pre = acc0[q] + acc1[q] + (float)xgl[lm][rowL];
      float a = (gt == 2) ? tanh_(pre) : sigm(pre);
      actl[rowL][lm] = a;
    }
    __syncthreads();

    // state update + publish
    {
      const int r = (g * 16 + bb) * 128 - WARM + s;
      const float iv = actl[uu][bb], fv = actl[32 + uu][bb];
      const float gv = actl[64 + uu][bb], ov = actl[96 + uu][bb];
      const float cOld = cst[uu][bb];
      float cN, hN;
      if (r >= 0) { cN = fv * cOld + iv * gv; hN = ov * tanh_(cN); }
      else        { cN = cOld; hN = h0v; }            // chunk-0 pre-roll: frozen at init
      cst[uu][bb] = cN;
      const unsigned int word = (((unsigned int)(s + 1) & 0xffffu) << 16)
                               | (unsigned int)f16bits(hN);
      unsigned int* wbuf = hstBase + (size_t)((s + 1) & 1) * (16 * 1024);
      __hip_atomic_store(&wbuf[bb * 1024 + ubase + uu], word,
                         __ATOMIC_RELAXED, __HIP_MEMORY_SCOPE_AGENT);
      if (s >= WARM) {
        const int t_ = d ? (8191 - r) : r;
        hist[(size_t)t_ * 1024 + ubase + uu] = (f16)hN;
      }
    }
    __syncthreads();
  }
}

// feats[t][n] = b_tag[n] + W_tag[n] . [hf[t], hb[t]]
__global__ void k_feats(const float* __restrict__ wtag, const float* __restrict__ btag,
                        char* __restrict__ ws) {
  const int idx = blockIdx.x * 256 + threadIdx.x;
  if (idx >= 8192 * 5) return;
  const int t = idx / 5, n = idx % 5;
  const f16* hf = (const f16*)(ws + HIST_OFF) + (size_t)t * 1024;
  const f16* hb = (const f16*)(ws + HIST_OFF) + (size_t)8192 * 1024 + (size_t)t * 1024;
  const float* wr = wtag + n * 2048;
  float acc = btag[n];
  for (int j = 0; j < 1024; j += 8) {
    v8h hv = *(const v8h*)(hf + j);
    #pragma unroll
    for (int i = 0; i < 8; i++) acc += wr[j + i] * (float)hv[i];
  }
  for (int j = 0; j < 1024; j += 8) {
    v8h hv = *(const v8h*)(hb + j);
    #pragma unroll
    for (int i = 0; i < 8; i++) acc += wr[1024 + j + i] * (float)hv[i];
  }
  ((float*)(ws + FEATS_OFF))[t * 8 + n] = acc;
}

// serial Viterbi forward scan: lanes 0..24 = (next n, prev p); START=3, STOP=4
__global__ void k_viterbi(const float* __restrict__ trans, char* __restrict__ ws,
                          float* __restrict__ out) {
  const float* feats = (const float*)(ws + FEATS_OFF);
  unsigned int* bpw = (unsigned int*)(ws + BPW_OFF);
  unsigned int* misc = (unsigned int*)(ws + MISC_OFF);
  __shared__ float ring[16][8];
  const int l = threadIdx.x;
  const int n = (l < 25) ? (l / 5) : 0;
  const int p = (l < 25) ? (l % 5) : 0;
  const float tr = trans[n * 5 + p];
  float fvp = (p == 3) ? 0.f : -1e8f;
  for (int i = 0; i < 8; i++) if (l < 8) ring[i][l] = (l < 5) ? feats[i * 8 + l] : 0.f;
  for (int t = 0; t < 8192; t++) {
    if (l < 8 && (t + 8) < 8192) ring[(t + 8) & 15][l] = feats[(t + 8) * 8 + l];
    float v = fvp + tr;
    float c0_ = __shfl(v, n * 5 + 0, 64), c1 = __shfl(v, n * 5 + 1, 64);
    float c2  = __shfl(v, n * 5 + 2, 64), c3 = __shfl(v, n * 5 + 3, 64);
    float c4  = __shfl(v, n * 5 + 4, 64);
    float m = fmaxf(fmaxf(fmaxf(c0_, c1), fmaxf(c2, c3)), c4);
    int bi_ = (c0_ == m) ? 0 : ((c1 == m) ? 1 : ((c2 == m) ? 2 : ((c3 == m) ? 3 : 4)));
    float nf = m + ring[t & 15][n];
    unsigned int word = (unsigned int)__shfl(bi_, 0, 64);
    word |= ((unsigned int)__shfl(bi_, 5, 64))  << 4;
    word |= ((unsigned int)__shfl(bi_, 10, 64)) << 8;
    word |= ((unsigned int)__shfl(bi_, 15, 64)) << 12;
    word |= ((unsigned int)__shfl(bi_, 20, 64)) << 16;
    if (l == 0) bpw[t] = word;
    fvp = __shfl(nf, p * 5, 64);
  }
  float term = fvp + trans[20 + p];
  float t0 = __shfl(term, 0, 64), t1 = __shfl(term, 1, 64), t2 = __shfl(term, 2, 64);
  float t3 = __shfl(term, 3, 64), t4 = __shfl(term, 4, 64);
  float tm = fmaxf(fmaxf(fmaxf(t0, t1), fmaxf(t2, t3)), t4);
  int bb = (t0 == tm) ? 0 : ((t1 == tm) ? 1 : ((t2 == tm) ? 2 : ((t3 == tm) ? 3 : 4)));
  if (l == 0) { out[0] = tm; misc[0] = (unsigned int)bb; }
}

// segmented parallel backtrack: 16 segments x 512 steps
__global__ void k_backtrack(char* __restrict__ ws, float* __restrict__ out) {
  __shared__ unsigned int bpl[8192];
  __shared__ unsigned char gtab[16][5];
  __shared__ unsigned char Echain[17];
  const int t = threadIdx.x;
  for (int i = t; i < 8192; i += 256) bpl[i] = ((unsigned int*)(ws + BPW_OFF))[i];
  __syncthreads();
  if (t < 80) {
    const int seg = t / 5, e = t % 5;
    int tag = e;
    for (int i = (seg + 1) * 512 - 1; i >= seg * 512; i--)
      tag = (int)((bpl[i] >> (4 * tag)) & 15u);
    gtab[seg][e] = (unsigned char)tag;
  }
  __syncthreads();
  if (t == 0) {
    int e = (int)((unsigned int*)(ws + MISC_OFF))[0];
    Echain[15] = (unsigned char)e;
    for (int s = 15; s >= 1; s--) Echain[s - 1] = gtab[s][Echain[s]];
  }
  __syncthreads();
  if (t < 16) {
    const int seg = t;
    int tag = Echain[seg];
    for (int i = (seg + 1) * 512 - 1; i >= seg * 512; i--) {
      out[1 + i] = (float)tag;                 // best_path[i] = tag_i
      tag = (int)((bpl[i] >> (4 * tag)) & 15u);
    }
  }
}

extern "C" void kernel_launch(void* const* d_in, const int* in_sizes, int n_in,
                              void* d_out, int out_size, void* d_ws, size_t ws_size,
                              hipStream_t stream) {
  const float* doc   = (const float*)d_in[0];
  const float* wih_f = (const float*)d_in[1];
  const float* whh_f = (const float*)d_in[2];
  const float* bih_f = (const float*)d_in[3];
  const float* bhh_f = (const float*)d_in[4];
  const float* wih_b = (const float*)d_in[5];
  const float* whh_b = (const float*)d_in[6];
  const float* bih_b = (const float*)d_in[7];
  const float* bhh_b = (const float*)d_in[8];
  const float* wtag  = (const float*)d_in[9];
  const float* btag  = (const float*)d_in[10];
  const float* trans = (const float*)d_in[11];
  const float* h0    = (const float*)d_in[12];
  const float* c0    = (const float*)d_in[13];
  float* out = (float*)d_out;
  char* ws = (char*)d_ws;
  (void)in_sizes; (void)n_in; (void)out_size;
  if (ws_size < WS_NEEDED) { k_sentinel<<<1, 64, 0, stream>>>(out); return; }
  k_prep<<<1024, 256, 0, stream>>>(whh_f, whh_b, ws);
  k_init<<<256, 256, 0, stream>>>(h0, ws);
  k_phase1<<<dim3(32, 64, 2), 256, 0, stream>>>(doc, wih_f, wih_b, bih_f, bhh_f,
                                                bih_b, bhh_b, ws);
  k_cluster<<<256, 512, 0, stream>>>(h0, c0, ws);
  k_feats<<<160, 256, 0, stream>>>(wtag, btag, ws);
  k_viterbi<<<1, 64, 0, stream>>>(trans, ws, out);
  k_backtrack<<<1, 256, 0, stream>>>(ws, out);
}